// Round 1
// baseline (804.813 us; speedup 1.0000x reference)
//
#include <hip/hip_runtime.h>
#include <math.h>

#define B_   4
#define S_   4096
#define IN_  4096
#define OUT_ 4096
#define RNK  8
#define K_   4

#define NBLK_A 512   // kernel-A blocks; 128 per batch, 32 rows each

// ---------------------------------------------------------------------------
// Kernel A: for each row (b,s): p[r] = x[b,s,:] . V[r,:]  (r=0..7)  -> xv
//           plus per-block column-sum partials of x (for the centroid).
// Layout: 8 waves/block, wave handles 4 rows (g = lane>>4), 16 j-lanes own
// 4 consecutive cols each -> 256B coalesced segments per row.
// ---------------------------------------------------------------------------
__global__ __launch_bounds__(512) void kA(const float* __restrict__ x,
                                          const float* __restrict__ V,
                                          float* __restrict__ colsum_part, // [NBLK_A][IN_]
                                          float* __restrict__ xv)          // [B_][S_][RNK]
{
    __shared__ float shcs[4 * IN_];  // per-g colsum slices (64 KB)
    const int tid = threadIdx.x;
    for (int c = tid; c < 4 * IN_; c += 512) shcs[c] = 0.f;
    __syncthreads();

    const int blk  = blockIdx.x;
    const int b    = blk >> 7;        // 128 blocks per batch
    const int sblk = blk & 127;
    const int w = tid >> 6, l = tid & 63, g = l >> 4, j = l & 15;
    const int s = sblk * 32 + w * 4 + g;
    const float* xr = x + ((size_t)(b * S_ + s)) * IN_;
    float* csg = shcs + g * IN_;

    float p[8] = {0.f,0.f,0.f,0.f,0.f,0.f,0.f,0.f};
    #pragma unroll 2
    for (int chunk = 0; chunk < 64; ++chunk) {
        const int col = chunk * 64 + j * 4;
        const float4 x4 = *(const float4*)(xr + col);
        #pragma unroll
        for (int r = 0; r < 8; ++r) {
            const float4 v4 = *(const float4*)(V + r * IN_ + col);
            p[r] += x4.x * v4.x + x4.y * v4.y + x4.z * v4.z + x4.w * v4.w;
        }
        // column-sum accumulation: per-g LDS slice, native fp32 LDS atomic.
        // Within one instruction all 64 lanes hit distinct addresses.
        unsafeAtomicAdd(csg + col + 0, x4.x);
        unsafeAtomicAdd(csg + col + 1, x4.y);
        unsafeAtomicAdd(csg + col + 2, x4.z);
        unsafeAtomicAdd(csg + col + 3, x4.w);
    }

    // reduce the 8 row-dots over the 16 j-lanes (butterfly, masks keep g bits)
    #pragma unroll
    for (int m = 1; m <= 8; m <<= 1) {
        #pragma unroll
        for (int r = 0; r < 8; ++r) p[r] += __shfl_xor(p[r], m, 64);
    }
    if (j == 0) {
        float* xvp = xv + ((size_t)(b * S_ + s)) * RNK;
        #pragma unroll
        for (int r = 0; r < 8; ++r) xvp[r] = p[r];
    }

    __syncthreads();
    // flush per-block colsum partial (sum the 4 g-slices)
    for (int c = tid * 4; c < IN_; c += 2048) {
        float4 a        = *(const float4*)(shcs + c);
        const float4 b4 = *(const float4*)(shcs + IN_ + c);
        const float4 c4 = *(const float4*)(shcs + 2 * IN_ + c);
        const float4 d4 = *(const float4*)(shcs + 3 * IN_ + c);
        a.x += b4.x + c4.x + d4.x;
        a.y += b4.y + c4.y + d4.y;
        a.z += b4.z + c4.z + d4.z;
        a.w += b4.w + c4.w + d4.w;
        *(float4*)(colsum_part + (size_t)blk * IN_ + c) = a;
    }
}

// ---------------------------------------------------------------------------
// Kernel B: one block per batch b. Reduces colsum partials -> centroid,
// cosine router + softmax(T=0.05), gate, Lam mixture, then
// P[b,o,r] = gate * sum_j U[o,j] * Lam[b,j,r].
// ---------------------------------------------------------------------------
__global__ __launch_bounds__(256) void kB(const float* __restrict__ x,
                                          const float* __restrict__ V,
                                          const float* __restrict__ U,
                                          const float* __restrict__ core_pool,
                                          const float* __restrict__ core_keys,
                                          const float* __restrict__ gate_w,
                                          const float* __restrict__ gate_b,
                                          const float* __restrict__ colsum_part,
                                          float* __restrict__ P) // [B_][OUT_][RNK]
{
    const int b = blockIdx.x, tid = threadIdx.x;
    float nrm2 = 0.f;
    float dotk[K_] = {0.f,0.f,0.f,0.f};
    float kn2[K_]  = {0.f,0.f,0.f,0.f};
    float us[8] = {0.f,0.f,0.f,0.f,0.f,0.f,0.f,0.f};
    float vs[8] = {0.f,0.f,0.f,0.f,0.f,0.f,0.f,0.f};

    const float ms = 0.3f / (float)S_;
    for (int it = 0; it < 4; ++it) {
        const int c = it * 1024 + tid * 4;
        float4 cs = {0.f,0.f,0.f,0.f};
        for (int pb = 0; pb < 128; ++pb) {
            const float4 t = *(const float4*)(colsum_part + ((size_t)(b * 128 + pb)) * IN_ + c);
            cs.x += t.x; cs.y += t.y; cs.z += t.z; cs.w += t.w;
        }
        const float4 xl = *(const float4*)(x + ((size_t)(b * S_ + S_ - 1)) * IN_ + c);
        float4 cen;
        cen.x = 0.7f * xl.x + ms * cs.x;
        cen.y = 0.7f * xl.y + ms * cs.y;
        cen.z = 0.7f * xl.z + ms * cs.z;
        cen.w = 0.7f * xl.w + ms * cs.w;
        nrm2 += cen.x*cen.x + cen.y*cen.y + cen.z*cen.z + cen.w*cen.w;
        #pragma unroll
        for (int k = 0; k < K_; ++k) {
            const float4 ck = *(const float4*)(core_keys + (size_t)k * IN_ + c);
            dotk[k] += cen.x*ck.x + cen.y*ck.y + cen.z*ck.z + cen.w*ck.w;
            kn2[k]  += ck.x*ck.x + ck.y*ck.y + ck.z*ck.z + ck.w*ck.w;
        }
    }
    for (int o = tid; o < OUT_; o += 256) {
        const float4 a  = *(const float4*)(U + (size_t)o * RNK);
        const float4 b4 = *(const float4*)(U + (size_t)o * RNK + 4);
        us[0]+=a.x;  us[1]+=a.y;  us[2]+=a.z;  us[3]+=a.w;
        us[4]+=b4.x; us[5]+=b4.y; us[6]+=b4.z; us[7]+=b4.w;
    }
    for (int it = 0; it < 4; ++it) {
        const int c = it * 1024 + tid * 4;
        #pragma unroll
        for (int r = 0; r < 8; ++r) {
            const float4 v = *(const float4*)(V + (size_t)r * IN_ + c);
            vs[r] += v.x + v.y + v.z + v.w;
        }
    }

    // block-reduce 25 scalars: wave shuffle then cross-wave via LDS
    __shared__ float red[25 * 4];
    __shared__ float res[25];
    float vals[25];
    vals[0] = nrm2;
    #pragma unroll
    for (int k = 0; k < K_; ++k) { vals[1 + k] = dotk[k]; vals[5 + k] = kn2[k]; }
    #pragma unroll
    for (int r = 0; r < 8; ++r) { vals[9 + r] = us[r]; vals[17 + r] = vs[r]; }
    const int wid = tid >> 6, lane = tid & 63;
    #pragma unroll
    for (int i = 0; i < 25; ++i) {
        float v = vals[i];
        #pragma unroll
        for (int m = 32; m >= 1; m >>= 1) v += __shfl_xor(v, m, 64);
        if (lane == 0) red[i * 4 + wid] = v;
    }
    __syncthreads();
    if (tid < 25) res[tid] = red[tid*4] + red[tid*4+1] + red[tid*4+2] + red[tid*4+3];
    __syncthreads();

    // router scalars (computed redundantly by every thread)
    const float ncen = fmaxf(sqrtf(res[0]), 1e-8f);
    float lg[K_], mx = -1e30f;
    #pragma unroll
    for (int k = 0; k < K_; ++k) {
        const float nk = fmaxf(sqrtf(res[5 + k]), 1e-8f);
        lg[k] = (res[1 + k] / (ncen * nk)) * 20.0f;   // /TEMP, TEMP=0.05
        mx = fmaxf(mx, lg[k]);
    }
    float wk[K_], se = 0.f;
    #pragma unroll
    for (int k = 0; k < K_; ++k) { wk[k] = expf(lg[k] - mx); se += wk[k]; }
    const float inv_se = 1.f / se;
    float z = gate_b[0];
    #pragma unroll
    for (int r = 0; r < 8; ++r) z += gate_w[r]     * (res[9 + r]  * (1.f / OUT_));
    #pragma unroll
    for (int r = 0; r < 8; ++r) z += gate_w[8 + r] * (res[17 + r] * (1.f / IN_));
    const float gate = 1.f / (1.f + expf(-z));

    __shared__ float Tsh[64];   // Tsh[j*8+r] = gate * Lam[b,j,r]
    if (tid < 64) {
        float acc = 0.f;
        #pragma unroll
        for (int k = 0; k < K_; ++k) acc += (wk[k] * inv_se) * core_pool[k * 64 + tid];
        Tsh[tid] = gate * acc;
    }
    __syncthreads();

    for (int o = tid; o < OUT_; o += 256) {
        const float4 a  = *(const float4*)(U + (size_t)o * RNK);
        const float4 b4 = *(const float4*)(U + (size_t)o * RNK + 4);
        const float u[8] = {a.x, a.y, a.z, a.w, b4.x, b4.y, b4.z, b4.w};
        float pr[8];
        #pragma unroll
        for (int r = 0; r < 8; ++r) {
            float acc = 0.f;
            #pragma unroll
            for (int jj = 0; jj < 8; ++jj) acc += u[jj] * Tsh[jj * 8 + r];
            pr[r] = acc;
        }
        *(float4*)(P + (size_t)(b * OUT_ + o) * RNK)     = make_float4(pr[0], pr[1], pr[2], pr[3]);
        *(float4*)(P + (size_t)(b * OUT_ + o) * RNK + 4) = make_float4(pr[4], pr[5], pr[6], pr[7]);
    }
}

// ---------------------------------------------------------------------------
// Kernel D: out[b,s,o] = sum_r P[b,o,r] * xv[b,s,r].  Write-bound.
// Block covers 2048 o-columns (2 float4 groups/thread), loops 16 s-rows.
// ---------------------------------------------------------------------------
__global__ __launch_bounds__(256) void kD(const float* __restrict__ P,
                                          const float* __restrict__ xv,
                                          float* __restrict__ out)
{
    const int blk = blockIdx.x;            // 2048 = B * 256 * 2
    const int b = blk >> 9, rem = blk & 511;
    const int half = rem >> 8, sc = rem & 255;
    const int t = threadIdx.x;
    const int oA = half * 2048 + t * 4;

    float PA[4][8], PB[4][8];
    #pragma unroll
    for (int u = 0; u < 4; ++u) {
        const float* pp = P + ((size_t)(b * OUT_ + oA + u)) * RNK;
        const float4 a = *(const float4*)pp;
        const float4 c = *(const float4*)(pp + 4);
        PA[u][0]=a.x; PA[u][1]=a.y; PA[u][2]=a.z; PA[u][3]=a.w;
        PA[u][4]=c.x; PA[u][5]=c.y; PA[u][6]=c.z; PA[u][7]=c.w;
        const float* pq = pp + (size_t)1024 * RNK;
        const float4 d = *(const float4*)pq;
        const float4 e = *(const float4*)(pq + 4);
        PB[u][0]=d.x; PB[u][1]=d.y; PB[u][2]=d.z; PB[u][3]=d.w;
        PB[u][4]=e.x; PB[u][5]=e.y; PB[u][6]=e.z; PB[u][7]=e.w;
    }

    const int srow0 = sc * 16;
    const float* xvp = xv + ((size_t)(b * S_ + srow0)) * RNK;
    float* op = out + ((size_t)(b * S_ + srow0)) * OUT_ + oA;
    #pragma unroll 4
    for (int row = 0; row < 16; ++row) {
        const float4 xa = *(const float4*)(xvp + row * RNK);
        const float4 xb = *(const float4*)(xvp + row * RNK + 4);
        const float xr[8] = {xa.x, xa.y, xa.z, xa.w, xb.x, xb.y, xb.z, xb.w};
        float accA[4], accB[4];
        #pragma unroll
        for (int u = 0; u < 4; ++u) {
            float sA = 0.f, sB = 0.f;
            #pragma unroll
            for (int r = 0; r < 8; ++r) { sA += PA[u][r] * xr[r]; sB += PB[u][r] * xr[r]; }
            accA[u] = sA; accB[u] = sB;
        }
        *(float4*)(op + (size_t)row * OUT_)        = make_float4(accA[0], accA[1], accA[2], accA[3]);
        *(float4*)(op + (size_t)row * OUT_ + 1024) = make_float4(accB[0], accB[1], accB[2], accB[3]);
    }
}

extern "C" void kernel_launch(void* const* d_in, const int* in_sizes, int n_in,
                              void* d_out, int out_size, void* d_ws, size_t ws_size,
                              hipStream_t stream) {
    const float* x         = (const float*)d_in[0];
    const float* V         = (const float*)d_in[1];
    const float* U         = (const float*)d_in[2];
    const float* core_pool = (const float*)d_in[3];
    const float* core_keys = (const float*)d_in[4];
    const float* gate_w    = (const float*)d_in[5];
    const float* gate_b    = (const float*)d_in[6];
    float* out = (float*)d_out;

    // workspace: xv [B,S,8] + P [B,OUT,8] = 1 MB
    float* xv = (float*)d_ws;
    float* P  = xv + (size_t)B_ * S_ * RNK;
    // colsum partials live in the tail of d_out (8 MB); kB consumes them
    // before kD overwrites the whole output (stream-ordered).
    float* colsum_part = out + ((size_t)out_size - (size_t)NBLK_A * IN_);

    kA<<<dim3(NBLK_A), dim3(512), 0, stream>>>(x, V, colsum_part, xv);
    kB<<<dim3(B_), dim3(256), 0, stream>>>(x, V, U, core_pool, core_keys,
                                           gate_w, gate_b, colsum_part, P);
    kD<<<dim3(2048), dim3(256), 0, stream>>>(P, xv, out);
}

// Round 2
// 603.976 us; speedup vs baseline: 1.3325x; 1.3325x over previous
//
#include <hip/hip_runtime.h>
#include <math.h>

#define B_   4
#define S_   4096
#define IN_  4096
#define OUT_ 4096
#define RNK  8
#define K_   4

#define NBLK_A 512   // kernel-A blocks; 128 per batch, 32 rows each

// ---------------------------------------------------------------------------
// zK: zero the global colsum accumulator (d_ws is poisoned every call).
// ---------------------------------------------------------------------------
__global__ __launch_bounds__(256) void zK(float* __restrict__ p) {
    p[blockIdx.x * 256 + threadIdx.x] = 0.f;
}

// ---------------------------------------------------------------------------
// Kernel A: for each row (b,s): p[r] = x[b,s,:] . V[r,:]  (r=0..7)  -> xv
//           plus column-sums of x accumulated into global colsum[b][IN_].
// Layout: 8 waves/block, wave handles 4 rows (g = lane>>4), 16 j-lanes own
// 4 consecutive cols each -> 256B coalesced segments per row.
// colsum path: butterfly over g (xor 16, xor 32) -> lanes l<16 hold the
// 4-row sums -> LDS atomicAdd (single 16KB array, <=2-way banks) -> one
// global unsafeAtomicAdd per column per block at the end.
// ---------------------------------------------------------------------------
__global__ __launch_bounds__(512) void kA(const float* __restrict__ x,
                                          const float* __restrict__ V,
                                          float* __restrict__ colsum,  // [B_][IN_]
                                          float* __restrict__ xv)      // [B_][S_][RNK]
{
    __shared__ float shcs[IN_];  // 16 KB block-level colsum
    const int tid = threadIdx.x;
    for (int c = tid; c < IN_; c += 512) shcs[c] = 0.f;
    __syncthreads();

    const int blk  = blockIdx.x;
    const int b    = blk >> 7;        // 128 blocks per batch
    const int sblk = blk & 127;
    const int w = tid >> 6, l = tid & 63, g = l >> 4, j = l & 15;
    const int s = sblk * 32 + w * 4 + g;
    const float* xr = x + ((size_t)(b * S_ + s)) * IN_;

    float p[8] = {0.f,0.f,0.f,0.f,0.f,0.f,0.f,0.f};
    #pragma unroll 4
    for (int chunk = 0; chunk < 64; ++chunk) {
        const int col = chunk * 64 + j * 4;
        const float4 x4 = *(const float4*)(xr + col);
        #pragma unroll
        for (int r = 0; r < 8; ++r) {
            const float4 v4 = *(const float4*)(V + r * IN_ + col);
            p[r] += x4.x * v4.x + x4.y * v4.y + x4.z * v4.z + x4.w * v4.w;
        }
        // reduce over the 4 g-rows in-register (lanes l<16 end with totals)
        float c0 = x4.x, c1 = x4.y, c2 = x4.z, c3 = x4.w;
        c0 += __shfl_xor(c0, 16); c1 += __shfl_xor(c1, 16);
        c2 += __shfl_xor(c2, 16); c3 += __shfl_xor(c3, 16);
        c0 += __shfl_xor(c0, 32); c1 += __shfl_xor(c1, 32);
        c2 += __shfl_xor(c2, 32); c3 += __shfl_xor(c3, 32);
        if (l < 16) {
            atomicAdd(&shcs[col + 0], c0);
            atomicAdd(&shcs[col + 1], c1);
            atomicAdd(&shcs[col + 2], c2);
            atomicAdd(&shcs[col + 3], c3);
        }
    }

    // reduce the 8 row-dots over the 16 j-lanes (butterfly)
    #pragma unroll
    for (int m = 1; m <= 8; m <<= 1) {
        #pragma unroll
        for (int r = 0; r < 8; ++r) p[r] += __shfl_xor(p[r], m);
    }
    float* xvp = xv + ((size_t)(b * S_ + s)) * RNK;
    if (j == 0) *(float4*)xvp       = make_float4(p[0], p[1], p[2], p[3]);
    if (j == 1) *(float4*)(xvp + 4) = make_float4(p[4], p[5], p[6], p[7]);

    __syncthreads();
    // flush per-block colsum into the global accumulator (fire-and-forget)
    for (int c = tid; c < IN_; c += 512)
        unsafeAtomicAdd(&colsum[(size_t)b * IN_ + c], shcs[c]);
}

// ---------------------------------------------------------------------------
// Kernel B: one block per batch b. colsum is already reduced -> centroid,
// cosine router + softmax(T=0.05), gate, Lam mixture, then
// P[b,o,r] = gate * sum_j U[o,j] * Lam[b,j,r].
// ---------------------------------------------------------------------------
__global__ __launch_bounds__(256) void kB(const float* __restrict__ x,
                                          const float* __restrict__ V,
                                          const float* __restrict__ U,
                                          const float* __restrict__ core_pool,
                                          const float* __restrict__ core_keys,
                                          const float* __restrict__ gate_w,
                                          const float* __restrict__ gate_b,
                                          const float* __restrict__ colsum,
                                          float* __restrict__ P) // [B_][OUT_][RNK]
{
    const int b = blockIdx.x, tid = threadIdx.x;
    float nrm2 = 0.f;
    float dotk[K_] = {0.f,0.f,0.f,0.f};
    float kn2[K_]  = {0.f,0.f,0.f,0.f};
    float us[8] = {0.f,0.f,0.f,0.f,0.f,0.f,0.f,0.f};
    float vs[8] = {0.f,0.f,0.f,0.f,0.f,0.f,0.f,0.f};

    const float ms = 0.3f / (float)S_;
    for (int it = 0; it < 4; ++it) {
        const int c = it * 1024 + tid * 4;
        const float4 cs = *(const float4*)(colsum + (size_t)b * IN_ + c);
        const float4 xl = *(const float4*)(x + ((size_t)(b * S_ + S_ - 1)) * IN_ + c);
        float4 cen;
        cen.x = 0.7f * xl.x + ms * cs.x;
        cen.y = 0.7f * xl.y + ms * cs.y;
        cen.z = 0.7f * xl.z + ms * cs.z;
        cen.w = 0.7f * xl.w + ms * cs.w;
        nrm2 += cen.x*cen.x + cen.y*cen.y + cen.z*cen.z + cen.w*cen.w;
        #pragma unroll
        for (int k = 0; k < K_; ++k) {
            const float4 ck = *(const float4*)(core_keys + (size_t)k * IN_ + c);
            dotk[k] += cen.x*ck.x + cen.y*ck.y + cen.z*ck.z + cen.w*ck.w;
            kn2[k]  += ck.x*ck.x + ck.y*ck.y + ck.z*ck.z + ck.w*ck.w;
        }
    }
    for (int o = tid; o < OUT_; o += 256) {
        const float4 a  = *(const float4*)(U + (size_t)o * RNK);
        const float4 b4 = *(const float4*)(U + (size_t)o * RNK + 4);
        us[0]+=a.x;  us[1]+=a.y;  us[2]+=a.z;  us[3]+=a.w;
        us[4]+=b4.x; us[5]+=b4.y; us[6]+=b4.z; us[7]+=b4.w;
    }
    for (int it = 0; it < 4; ++it) {
        const int c = it * 1024 + tid * 4;
        #pragma unroll
        for (int r = 0; r < 8; ++r) {
            const float4 v = *(const float4*)(V + (size_t)r * IN_ + c);
            vs[r] += v.x + v.y + v.z + v.w;
        }
    }

    // block-reduce 25 scalars: wave shuffle then cross-wave via LDS
    __shared__ float red[25 * 4];
    __shared__ float res[25];
    float vals[25];
    vals[0] = nrm2;
    #pragma unroll
    for (int k = 0; k < K_; ++k) { vals[1 + k] = dotk[k]; vals[5 + k] = kn2[k]; }
    #pragma unroll
    for (int r = 0; r < 8; ++r) { vals[9 + r] = us[r]; vals[17 + r] = vs[r]; }
    const int wid = tid >> 6, lane = tid & 63;
    #pragma unroll
    for (int i = 0; i < 25; ++i) {
        float v = vals[i];
        #pragma unroll
        for (int m = 32; m >= 1; m >>= 1) v += __shfl_xor(v, m);
        if (lane == 0) red[i * 4 + wid] = v;
    }
    __syncthreads();
    if (tid < 25) res[tid] = red[tid*4] + red[tid*4+1] + red[tid*4+2] + red[tid*4+3];
    __syncthreads();

    // router scalars (computed redundantly by every thread)
    const float ncen = fmaxf(sqrtf(res[0]), 1e-8f);
    float lg[K_], mx = -1e30f;
    #pragma unroll
    for (int k = 0; k < K_; ++k) {
        const float nk = fmaxf(sqrtf(res[5 + k]), 1e-8f);
        lg[k] = (res[1 + k] / (ncen * nk)) * 20.0f;   // /TEMP, TEMP=0.05
        mx = fmaxf(mx, lg[k]);
    }
    float wk[K_], se = 0.f;
    #pragma unroll
    for (int k = 0; k < K_; ++k) { wk[k] = expf(lg[k] - mx); se += wk[k]; }
    const float inv_se = 1.f / se;
    float z = gate_b[0];
    #pragma unroll
    for (int r = 0; r < 8; ++r) z += gate_w[r]     * (res[9 + r]  * (1.f / OUT_));
    #pragma unroll
    for (int r = 0; r < 8; ++r) z += gate_w[8 + r] * (res[17 + r] * (1.f / IN_));
    const float gate = 1.f / (1.f + expf(-z));

    __shared__ float Tsh[64];   // Tsh[j*8+r] = gate * Lam[b,j,r]
    if (tid < 64) {
        float acc = 0.f;
        #pragma unroll
        for (int k = 0; k < K_; ++k) acc += (wk[k] * inv_se) * core_pool[k * 64 + tid];
        Tsh[tid] = gate * acc;
    }
    __syncthreads();

    for (int o = tid; o < OUT_; o += 256) {
        const float4 a  = *(const float4*)(U + (size_t)o * RNK);
        const float4 b4 = *(const float4*)(U + (size_t)o * RNK + 4);
        const float u[8] = {a.x, a.y, a.z, a.w, b4.x, b4.y, b4.z, b4.w};
        float pr[8];
        #pragma unroll
        for (int r = 0; r < 8; ++r) {
            float acc = 0.f;
            #pragma unroll
            for (int jj = 0; jj < 8; ++jj) acc += u[jj] * Tsh[jj * 8 + r];
            pr[r] = acc;
        }
        *(float4*)(P + (size_t)(b * OUT_ + o) * RNK)     = make_float4(pr[0], pr[1], pr[2], pr[3]);
        *(float4*)(P + (size_t)(b * OUT_ + o) * RNK + 4) = make_float4(pr[4], pr[5], pr[6], pr[7]);
    }
}

// ---------------------------------------------------------------------------
// Kernel D: out[b,s,o] = sum_r P[b,o,r] * xv[b,s,r].  Write-bound.
// Block covers 2048 o-columns (2 float4 groups/thread), loops 16 s-rows.
// ---------------------------------------------------------------------------
__global__ __launch_bounds__(256) void kD(const float* __restrict__ P,
                                          const float* __restrict__ xv,
                                          float* __restrict__ out)
{
    const int blk = blockIdx.x;            // 2048 = B * 256 * 2
    const int b = blk >> 9, rem = blk & 511;
    const int half = rem >> 8, sc = rem & 255;
    const int t = threadIdx.x;
    const int oA = half * 2048 + t * 4;

    float PA[4][8], PB[4][8];
    #pragma unroll
    for (int u = 0; u < 4; ++u) {
        const float* pp = P + ((size_t)(b * OUT_ + oA + u)) * RNK;
        const float4 a = *(const float4*)pp;
        const float4 c = *(const float4*)(pp + 4);
        PA[u][0]=a.x; PA[u][1]=a.y; PA[u][2]=a.z; PA[u][3]=a.w;
        PA[u][4]=c.x; PA[u][5]=c.y; PA[u][6]=c.z; PA[u][7]=c.w;
        const float* pq = pp + (size_t)1024 * RNK;
        const float4 d = *(const float4*)pq;
        const float4 e = *(const float4*)(pq + 4);
        PB[u][0]=d.x; PB[u][1]=d.y; PB[u][2]=d.z; PB[u][3]=d.w;
        PB[u][4]=e.x; PB[u][5]=e.y; PB[u][6]=e.z; PB[u][7]=e.w;
    }

    const int srow0 = sc * 16;
    const float* xvp = xv + ((size_t)(b * S_ + srow0)) * RNK;
    float* op = out + ((size_t)(b * S_ + srow0)) * OUT_ + oA;
    #pragma unroll 4
    for (int row = 0; row < 16; ++row) {
        const float4 xa = *(const float4*)(xvp + row * RNK);
        const float4 xb = *(const float4*)(xvp + row * RNK + 4);
        const float xr[8] = {xa.x, xa.y, xa.z, xa.w, xb.x, xb.y, xb.z, xb.w};
        float accA[4], accB[4];
        #pragma unroll
        for (int u = 0; u < 4; ++u) {
            float sA = 0.f, sB = 0.f;
            #pragma unroll
            for (int r = 0; r < 8; ++r) { sA += PA[u][r] * xr[r]; sB += PB[u][r] * xr[r]; }
            accA[u] = sA; accB[u] = sB;
        }
        *(float4*)(op + (size_t)row * OUT_)        = make_float4(accA[0], accA[1], accA[2], accA[3]);
        *(float4*)(op + (size_t)row * OUT_ + 1024) = make_float4(accB[0], accB[1], accB[2], accB[3]);
    }
}

extern "C" void kernel_launch(void* const* d_in, const int* in_sizes, int n_in,
                              void* d_out, int out_size, void* d_ws, size_t ws_size,
                              hipStream_t stream) {
    const float* x         = (const float*)d_in[0];
    const float* V         = (const float*)d_in[1];
    const float* U         = (const float*)d_in[2];
    const float* core_pool = (const float*)d_in[3];
    const float* core_keys = (const float*)d_in[4];
    const float* gate_w    = (const float*)d_in[5];
    const float* gate_b    = (const float*)d_in[6];
    float* out = (float*)d_out;

    // workspace layout: colsum [B,IN] + xv [B,S,8] + P [B,OUT,8]  (~1.1 MB)
    float* colsum = (float*)d_ws;
    float* xv = colsum + (size_t)B_ * IN_;
    float* P  = xv + (size_t)B_ * S_ * RNK;

    zK<<<dim3((B_ * IN_) / 256), dim3(256), 0, stream>>>(colsum);
    kA<<<dim3(NBLK_A), dim3(512), 0, stream>>>(x, V, colsum, xv);
    kB<<<dim3(B_), dim3(256), 0, stream>>>(x, V, U, core_pool, core_keys,
                                           gate_w, gate_b, colsum, P);
    kD<<<dim3(2048), dim3(256), 0, stream>>>(P, xv, out);
}